// Round 4
// baseline (15233.058 us; speedup 1.0000x reference)
//
#include <hip/hip_runtime.h>
#include <hip/hip_bf16.h>
#include <math.h>

#define BATCH 256
#define T_IN 256
#define T_OUT 32
#define E_DIM 512
#define H_DIM 1024
#define Y_DIM 1024
#define G_DIM 3072  // 3*H

typedef __attribute__((ext_vector_type(8))) __bf16 bf16x8;
typedef __attribute__((ext_vector_type(4))) float f32x4;
typedef __attribute__((ext_vector_type(4))) unsigned int u32x4;

__device__ __forceinline__ unsigned short f2bf_raw(float x) {
    unsigned int u = __builtin_bit_cast(unsigned int, x);
    u += 0x7FFFu + ((u >> 16) & 1u);
    return (unsigned short)(u >> 16);
}
__device__ __forceinline__ float bf2f(short s) {
    unsigned int u = ((unsigned int)(unsigned short)s) << 16;
    return __builtin_bit_cast(float, u);
}
__device__ __forceinline__ f32x4 mfma16(bf16x8 a, bf16x8 b, f32x4 c) {
    return __builtin_amdgcn_mfma_f32_16x16x32_bf16(a, b, c, 0, 0, 0);
}
__device__ __forceinline__ bf16x8 ldsb8(const short* p) {
    return __builtin_bit_cast(bf16x8, *(const u32x4*)p);
}

// ---------------------------------------------------------------------------
// f32 -> bf16 convert (weights, once per call)
// ---------------------------------------------------------------------------
__global__ __launch_bounds__(256) void f32_to_bf16(
    const float* __restrict__ src, short* __restrict__ dst, int n4)
{
    for (int i = blockIdx.x * 256 + threadIdx.x; i < n4; i += gridDim.x * 256) {
        float4 f = *(const float4*)(src + 4 * (size_t)i);
        short4 o;
        o.x = (short)f2bf_raw(f.x);
        o.y = (short)f2bf_raw(f.y);
        o.z = (short)f2bf_raw(f.z);
        o.w = (short)f2bf_raw(f.w);
        *(short4*)(dst + 4 * (size_t)i) = o;
    }
}

// ---------------------------------------------------------------------------
// Fused GRU cell: full GEMM (gi = A@Wih^T, gh = h@Whh^T) + GRU elementwise
// in the epilogue. Two independent cells per launch via blockIdx.z
// (diagonal layer pipelining). Tile: 32 rows x 64 h-cols x {3 gates x 2 src}.
// ---------------------------------------------------------------------------
struct CellArgs {
    const float* Af; const short* Ab; const int* gat; int gs; int lda; int Kx;
    const short* Wih; const short* Whh;
    const float* bih; const float* bhh;
    const short* hbf;   // bf16 h_prev (GEMM input)
    const float* hf;    // f32  h_prev (GRU combine)
    float* houtf; short* houtbf; short* copy;
    int active;
};

__global__ __launch_bounds__(256) void cell_kernel(CellArgs cA, CellArgs cB)
{
    const CellArgs a = blockIdx.z ? cB : cA;
    if (!a.active) return;

    __shared__ __align__(16) short As[2 * 1280];   // [src][32 rows][40]
    __shared__ __align__(16) short Ws[6 * 2560];   // [wt][64 rows][40]

    const int tid = threadIdx.x;
    const int bm = blockIdx.x * 32;
    const int bn = blockIdx.y * 64;

    // staging: pass0 = A tiles (256 chunks), pass1..6 = W tiles (256 each)
    const int sr = (tid >> 2) & 31;   // A row
    const int ss = tid >> 7;          // A src (0=x, 1=h)
    const int wr = tid >> 2;          // W row 0..63
    const int ch = (tid & 3) * 8;     // 8-short (16B) chunk offset

    const float* axf = nullptr;
    const short* axb = nullptr;
    if (a.Af) {
        int ridx = a.gat ? a.gat[(size_t)(bm + sr) * a.gs] : (bm + sr);
        axf = a.Af + (size_t)ridx * a.lda + ch;
    } else if (a.Ab) {
        axb = a.Ab + (size_t)(bm + sr) * a.lda + ch;
    }
    const short* ahb = a.hbf + (size_t)(bm + sr) * H_DIM + ch;

    const short* wsrc[6];
    #pragma unroll
    for (int g = 0; g < 3; ++g) {
        wsrc[g]     = a.Wih + (size_t)(g * H_DIM + bn + wr) * a.Kx + ch;
        wsrc[g + 3] = a.Whh + (size_t)(g * H_DIM + bn + wr) * H_DIM + ch;
    }
    short* adst  = &As[ss * 1280 + sr * 40 + ch];
    short* wdst0 = &Ws[wr * 40 + ch];

    const int lane = tid & 63;
    const int w = tid >> 6;
    const int lr = lane & 15;
    const int ko = (lane >> 4) * 8;
    const short* pax0 = &As[lr * 40 + ko];
    const short* pax1 = &As[(16 + lr) * 40 + ko];
    const short* pah0 = &As[1280 + lr * 40 + ko];
    const short* pah1 = &As[1280 + (16 + lr) * 40 + ko];
    const int wc = (w * 16 + lr) * 40 + ko;

    f32x4 accI[3][2] = {{{0.f,0.f,0.f,0.f}}};
    f32x4 accH[3][2] = {{{0.f,0.f,0.f,0.f}}};

    const int Kx = a.Kx;
    for (int k0 = 0; k0 < H_DIM; k0 += 32) {
        const bool xact = (k0 < Kx);
        // ---- stage ----
        u32x4 av = {0u, 0u, 0u, 0u};
        if (ss) {
            av = *(const u32x4*)(ahb + k0);
        } else if (xact) {
            if (axb) {
                av = *(const u32x4*)(axb + k0);
            } else if (axf) {
                float4 f0 = *(const float4*)(axf + k0);
                float4 f1 = *(const float4*)(axf + k0 + 4);
                av.x = ((unsigned)f2bf_raw(f0.y) << 16) | f2bf_raw(f0.x);
                av.y = ((unsigned)f2bf_raw(f0.w) << 16) | f2bf_raw(f0.z);
                av.z = ((unsigned)f2bf_raw(f1.y) << 16) | f2bf_raw(f1.x);
                av.w = ((unsigned)f2bf_raw(f1.w) << 16) | f2bf_raw(f1.z);
            }
        }
        if (ss || xact) *(u32x4*)adst = av;
        #pragma unroll
        for (int i = 0; i < 6; ++i) {
            if (i >= 3 || xact)
                *(u32x4*)(wdst0 + i * 2560) = *(const u32x4*)(wsrc[i] + k0);
        }
        __syncthreads();
        // ---- compute ----
        bf16x8 ah0 = ldsb8(pah0), ah1 = ldsb8(pah1);
        #pragma unroll
        for (int g = 0; g < 3; ++g) {
            bf16x8 wh = ldsb8(&Ws[(g + 3) * 2560 + wc]);
            accH[g][0] = mfma16(ah0, wh, accH[g][0]);
            accH[g][1] = mfma16(ah1, wh, accH[g][1]);
        }
        if (xact) {
            bf16x8 ax0 = ldsb8(pax0), ax1 = ldsb8(pax1);
            #pragma unroll
            for (int g = 0; g < 3; ++g) {
                bf16x8 wi = ldsb8(&Ws[g * 2560 + wc]);
                accI[g][0] = mfma16(ax0, wi, accI[g][0]);
                accI[g][1] = mfma16(ax1, wi, accI[g][1]);
            }
        }
        __syncthreads();
    }

    // ---- GRU epilogue (torch gate order r,z,n) ----
    const int j = bn + w * 16 + lr;
    const float bi0 = a.bih[j], bi1 = a.bih[H_DIM + j], bi2 = a.bih[2 * H_DIM + j];
    const float bh0 = a.bhh[j], bh1 = a.bhh[H_DIM + j], bh2 = a.bhh[2 * H_DIM + j];
    #pragma unroll
    for (int rh = 0; rh < 2; ++rh) {
        #pragma unroll
        for (int q = 0; q < 4; ++q) {
            int row = bm + rh * 16 + (lane >> 4) * 4 + q;
            float ir = accI[0][rh][q] + bi0, hr = accH[0][rh][q] + bh0;
            float iz = accI[1][rh][q] + bi1, hz = accH[1][rh][q] + bh1;
            float in_ = accI[2][rh][q] + bi2, hn = accH[2][rh][q] + bh2;
            float r = 1.f / (1.f + expf(-(ir + hr)));
            float z = 1.f / (1.f + expf(-(iz + hz)));
            float n = tanhf(in_ + r * hn);
            size_t oi = (size_t)row * H_DIM + j;
            float hv = a.hf[oi];
            float o = (1.f - z) * n + z * hv;
            a.houtf[oi] = o;
            short ob = (short)f2bf_raw(o);
            a.houtbf[oi] = ob;
            if (a.copy) a.copy[oi] = ob;
        }
    }
}

// ---------------------------------------------------------------------------
// scores: S[b][t][s] = dot(h2all[t][b][:], enc[s][b][:]) — MFMA, all t at once
// grid (4 s-tiles, 256 b)
// ---------------------------------------------------------------------------
__global__ __launch_bounds__(256) void score_gemm(
    const short* __restrict__ h2all, const short* __restrict__ enc,
    float* __restrict__ S)
{
    const int st = blockIdx.x;
    const int b = blockIdx.y;
    __shared__ __align__(16) short Hs[32 * 40];
    __shared__ __align__(16) short Es[64 * 40];
    const int tid = threadIdx.x;
    const int ch = (tid & 3) * 8;
    const int hrow = (tid >> 2) & 31;
    const int erow = tid >> 2;
    const short* hsrc = h2all + ((size_t)hrow * BATCH + b) * H_DIM + ch;
    const short* esrc = enc + ((size_t)(st * 64 + erow) * BATCH + b) * H_DIM + ch;
    short* hdst = &Hs[hrow * 40 + ch];
    short* edst = &Es[erow * 40 + ch];

    const int lane = tid & 63, w = tid >> 6;
    const int lr = lane & 15, ko = (lane >> 4) * 8;
    f32x4 acc0 = {0.f, 0.f, 0.f, 0.f}, acc1 = acc0;
    for (int k0 = 0; k0 < H_DIM; k0 += 32) {
        if (tid < 128) *(u32x4*)hdst = *(const u32x4*)(hsrc + k0);
        *(u32x4*)edst = *(const u32x4*)(esrc + k0);
        __syncthreads();
        bf16x8 e = ldsb8(&Es[(w * 16 + lr) * 40 + ko]);
        bf16x8 h0v = ldsb8(&Hs[lr * 40 + ko]);
        bf16x8 h1v = ldsb8(&Hs[(16 + lr) * 40 + ko]);
        acc0 = mfma16(h0v, e, acc0);
        acc1 = mfma16(h1v, e, acc1);
        __syncthreads();
    }
    int s = st * 64 + w * 16 + lr;
    #pragma unroll
    for (int q = 0; q < 4; ++q) {
        int t0 = (lane >> 4) * 4 + q;
        S[(size_t)b * 8192 + (size_t)t0 * 256 + s] = acc0[q];
        S[(size_t)b * 8192 + (size_t)(t0 + 16) * 256 + s] = acc1[q];
    }
}

// softmax over s (256) per (b,t) row; grid 8192
__global__ __launch_bounds__(256) void softmax_all(float* __restrict__ S)
{
    size_t base = (size_t)blockIdx.x * 256;
    int t = threadIdx.x;
    float v = S[base + t];
    int lane = t & 63, w = t >> 6;
    float m = v;
    for (int off = 32; off; off >>= 1) m = fmaxf(m, __shfl_down(m, off));
    __shared__ float r1[4];
    if (!lane) r1[w] = m;
    __syncthreads();
    m = fmaxf(fmaxf(r1[0], r1[1]), fmaxf(r1[2], r1[3]));
    float ex = expf(v - m);
    float s = ex;
    for (int off = 32; off; off >>= 1) s += __shfl_down(s, off);
    __shared__ float r2[4];
    if (!lane) r2[w] = s;
    __syncthreads();
    s = r2[0] + r2[1] + r2[2] + r2[3];
    S[base + t] = ex / s;
}

// attn_bf[m=t*256+b][h] = sum_s alpha[b][t][s] * enc[s][b][h]; grid (4 tc, 256 b)
__global__ __launch_bounds__(256) void attn_apply_all(
    const short* __restrict__ enc, const float* __restrict__ S,
    short* __restrict__ attn_bf)
{
    const int tc = blockIdx.x, b = blockIdx.y;
    __shared__ float al[8][256];
    const int tid = threadIdx.x;
    #pragma unroll
    for (int ti = 0; ti < 8; ++ti)
        al[ti][tid] = S[(size_t)b * 8192 + (size_t)(tc * 8 + ti) * 256 + tid];
    __syncthreads();
    float acc[8][4] = {};
    const short* eb = enc + (size_t)b * H_DIM + tid;
    for (int s = 0; s < 256; ++s) {
        const short* er = eb + (size_t)s * (BATCH * H_DIM);
        float e0 = bf2f(er[0]), e1 = bf2f(er[256]);
        float e2 = bf2f(er[512]), e3 = bf2f(er[768]);
        #pragma unroll
        for (int ti = 0; ti < 8; ++ti) {
            float av = al[ti][s];
            acc[ti][0] += av * e0; acc[ti][1] += av * e1;
            acc[ti][2] += av * e2; acc[ti][3] += av * e3;
        }
    }
    #pragma unroll
    for (int ti = 0; ti < 8; ++ti) {
        size_t m = (size_t)(tc * 8 + ti) * 256 + b;
        #pragma unroll
        for (int i = 0; i < 4; ++i)
            attn_bf[m * H_DIM + tid + i * 256] = (short)f2bf_raw(acc[ti][i]);
    }
}

// ---------------------------------------------------------------------------
// logits[m][n] = attn[m]@mapW[n][:1024] + h2[m]@mapW[n][1024:] + b[n]
// grid (128, 16), tile 64x64
// ---------------------------------------------------------------------------
__global__ __launch_bounds__(256) void map_gemm(
    const short* __restrict__ A1, const short* __restrict__ A2,
    const short* __restrict__ Wm, const float* __restrict__ bias,
    float* __restrict__ C)
{
    const int bm = blockIdx.x * 64, bn = blockIdx.y * 64;
    __shared__ __align__(16) short S1[64 * 40], S2[64 * 40], T1[64 * 40], T2[64 * 40];
    const int tid = threadIdx.x;
    const int r = tid >> 2, ch = (tid & 3) * 8;
    const short* a1 = A1 + (size_t)(bm + r) * 1024 + ch;
    const short* a2 = A2 + (size_t)(bm + r) * 1024 + ch;
    const short* w1 = Wm + (size_t)(bn + r) * 2048 + ch;
    const short* w2 = w1 + 1024;
    const int lane = tid & 63, w = tid >> 6;
    const int wm = (w >> 1) * 32, wn = (w & 1) * 32;
    const int lr = lane & 15, ko = (lane >> 4) * 8;
    f32x4 acc[2][2] = {{{0.f,0.f,0.f,0.f}}};
    for (int k0 = 0; k0 < 1024; k0 += 32) {
        *(u32x4*)&S1[r * 40 + ch] = *(const u32x4*)(a1 + k0);
        *(u32x4*)&S2[r * 40 + ch] = *(const u32x4*)(a2 + k0);
        *(u32x4*)&T1[r * 40 + ch] = *(const u32x4*)(w1 + k0);
        *(u32x4*)&T2[r * 40 + ch] = *(const u32x4*)(w2 + k0);
        __syncthreads();
        bf16x8 x1[2], x2[2], y1[2], y2[2];
        #pragma unroll
        for (int i = 0; i < 2; ++i) {
            x1[i] = ldsb8(&S1[(wm + i * 16 + lr) * 40 + ko]);
            x2[i] = ldsb8(&S2[(wm + i * 16 + lr) * 40 + ko]);
            y1[i] = ldsb8(&T1[(wn + i * 16 + lr) * 40 + ko]);
            y2[i] = ldsb8(&T2[(wn + i * 16 + lr) * 40 + ko]);
        }
        #pragma unroll
        for (int i = 0; i < 2; ++i) {
            #pragma unroll
            for (int jq = 0; jq < 2; ++jq) {
                acc[i][jq] = mfma16(x1[i], y1[jq], acc[i][jq]);
                acc[i][jq] = mfma16(x2[i], y2[jq], acc[i][jq]);
            }
        }
        __syncthreads();
    }
    #pragma unroll
    for (int i = 0; i < 2; ++i) {
        #pragma unroll
        for (int jq = 0; jq < 2; ++jq) {
            int col = bn + wn + jq * 16 + lr;
            float bv = bias[col];
            #pragma unroll
            for (int q = 0; q < 4; ++q) {
                int row = bm + wm + i * 16 + (lane >> 4) * 4 + q;
                C[(size_t)row * 1024 + col] = acc[i][jq][q] + bv;
            }
        }
    }
}

// loss over all (t,b) rows; grid 8192, m = t*256+b
__global__ __launch_bounds__(256) void loss_all(
    const float* __restrict__ logits, const float* __restrict__ y,
    float* __restrict__ loss_acc)
{
    int m = blockIdx.x, t = threadIdx.x;
    int tt = m >> 8, b = m & 255;
    const float* lrow = logits + (size_t)m * Y_DIM;
    float l[4];
    #pragma unroll
    for (int i = 0; i < 4; ++i) l[i] = lrow[t + i * 256];
    float mx = fmaxf(fmaxf(l[0], l[1]), fmaxf(l[2], l[3]));
    int lane = t & 63, w = t >> 6;
    for (int off = 32; off; off >>= 1) mx = fmaxf(mx, __shfl_down(mx, off));
    __shared__ float sm[4];
    if (!lane) sm[w] = mx;
    __syncthreads();
    mx = fmaxf(fmaxf(sm[0], sm[1]), fmaxf(sm[2], sm[3]));
    float es = 0.f;
    #pragma unroll
    for (int i = 0; i < 4; ++i) es += expf(l[i] - mx);
    for (int off = 32; off; off >>= 1) es += __shfl_down(es, off);
    __shared__ float ss[4];
    if (!lane) ss[w] = es;
    __syncthreads();
    float sum = ss[0] + ss[1] + ss[2] + ss[3];
    float logZ = mx + logf(sum);
    const float* yrow = y + ((size_t)b * T_OUT + tt) * Y_DIM;
    float part = 0.f;
    #pragma unroll
    for (int i = 0; i < 4; ++i) part += yrow[t + i * 256] * (logZ - l[i]);
    for (int off = 32; off; off >>= 1) part += __shfl_down(part, off);
    __shared__ float sp[4];
    if (!lane) sp[w] = part;
    __syncthreads();
    if (t == 0) atomicAdd(loss_acc, sp[0] + sp[1] + sp[2] + sp[3]);
}

__global__ __launch_bounds__(256) void ysum_kernel(
    const float* __restrict__ y, float* __restrict__ ysum, int n)
{
    float s = 0.f;
    for (int i = blockIdx.x * 256 + threadIdx.x; i < n; i += gridDim.x * 256)
        s += y[i];
    int lane = threadIdx.x & 63, w = threadIdx.x >> 6;
    for (int off = 32; off; off >>= 1) s += __shfl_down(s, off);
    __shared__ float sw[4];
    if (!lane) sw[w] = s;
    __syncthreads();
    if (!threadIdx.x) atomicAdd(ysum, sw[0] + sw[1] + sw[2] + sw[3]);
}

__global__ __launch_bounds__(256) void init_kernel(
    float* __restrict__ h0, float* __restrict__ h1,
    short* __restrict__ h0b, short* __restrict__ h1b,
    float* __restrict__ loss, float* __restrict__ ysum)
{
    int i = blockIdx.x * 256 + threadIdx.x;   // 0..B*H-1
    h0[i] = 0.f; h1[i] = 0.f; h0b[i] = 0; h1b[i] = 0;
    if (i == 0) { *loss = 0.f; *ysum = 0.f; }
}

__global__ void final_kernel(const float* __restrict__ loss,
                             const float* __restrict__ ysum,
                             float* __restrict__ out)
{
    if (threadIdx.x == 0) out[0] = loss[0] / ysum[0];
}

// ---------------------------------------------------------------------------
extern "C" void kernel_launch(void* const* d_in, const int* in_sizes, int n_in,
                              void* d_out, int out_size, void* d_ws, size_t ws_size,
                              hipStream_t stream)
{
    const int*   x     = (const int*)d_in[0];
    const float* y     = (const float*)d_in[1];
    const float* emb   = (const float*)d_in[2];
    const float* eWih0 = (const float*)d_in[3];
    const float* eWhh0 = (const float*)d_in[4];
    const float* ebih0 = (const float*)d_in[5];
    const float* ebhh0 = (const float*)d_in[6];
    const float* eWih1 = (const float*)d_in[7];
    const float* eWhh1 = (const float*)d_in[8];
    const float* ebih1 = (const float*)d_in[9];
    const float* ebhh1 = (const float*)d_in[10];
    const float* dWih0 = (const float*)d_in[11];
    const float* dWhh0 = (const float*)d_in[12];
    const float* dbih0 = (const float*)d_in[13];
    const float* dbhh0 = (const float*)d_in[14];
    const float* dWih1 = (const float*)d_in[15];
    const float* dWhh1 = (const float*)d_in[16];
    const float* dbih1 = (const float*)d_in[17];
    const float* dbhh1 = (const float*)d_in[18];
    const float* mapW  = (const float*)d_in[19];
    const float* mapb  = (const float*)d_in[20];
    float* out = (float*)d_out;

    // ---- workspace layout (~209 MB live peak; aliases reuse dead regions) ----
    char* p = (char*)d_ws;
    auto take = [&](size_t n) { char* q = p; p += (n + 255) & ~(size_t)255; return q; };
    short* enc_bf = (short*)take((size_t)T_IN * BATCH * H_DIM * 2);   // 134 MB
    char* wslab = p;
    short* eWih0b = (short*)take((size_t)G_DIM * E_DIM * 2);
    short* eWhh0b = (short*)take((size_t)G_DIM * H_DIM * 2);
    short* eWih1b = (short*)take((size_t)G_DIM * H_DIM * 2);
    short* eWhh1b = (short*)take((size_t)G_DIM * H_DIM * 2);
    short* dWih0b = (short*)take((size_t)G_DIM * Y_DIM * 2);
    short* dWhh0b = (short*)take((size_t)G_DIM * H_DIM * 2);
    short* dWih1b = (short*)take((size_t)G_DIM * H_DIM * 2);
    short* dWhh1b = (short*)take((size_t)G_DIM * H_DIM * 2);
    short* mapWb  = (short*)take((size_t)Y_DIM * 2 * H_DIM * 2);
    float* h0f[2]; float* h1f[2]; short* h0b[2]; short* h1b[2];
    for (int i = 0; i < 2; ++i) {
        h0f[i] = (float*)take((size_t)BATCH * H_DIM * 4);
        h1f[i] = (float*)take((size_t)BATCH * H_DIM * 4);
        h0b[i] = (short*)take((size_t)BATCH * H_DIM * 2);
        h1b[i] = (short*)take((size_t)BATCH * H_DIM * 2);
    }
    short* h2all = (short*)take((size_t)T_OUT * BATCH * H_DIM * 2);   // 16.8 MB
    float* loss_acc = (float*)take(256);
    float* ysum = loss_acc + 1;
    // aliases onto dead regions:
    float* logits  = (float*)enc_bf;                       // 32 MB; enc dead at map time
    short* attn_bf = (short*)wslab;                        // 16.8 MB over dead enc weights
    float* S       = (float*)(wslab + (size_t)20 * 1024 * 1024);  // 8.4 MB, < mapWb offset

    dim3 blk(256);

    // ---- weight conversion ----
    f32_to_bf16<<<dim3(512), blk, 0, stream>>>(eWih0, eWih0b, G_DIM * E_DIM / 4);
    f32_to_bf16<<<dim3(512), blk, 0, stream>>>(eWhh0, eWhh0b, G_DIM * H_DIM / 4);
    f32_to_bf16<<<dim3(512), blk, 0, stream>>>(eWih1, eWih1b, G_DIM * H_DIM / 4);
    f32_to_bf16<<<dim3(512), blk, 0, stream>>>(eWhh1, eWhh1b, G_DIM * H_DIM / 4);
    f32_to_bf16<<<dim3(512), blk, 0, stream>>>(dWih0, dWih0b, G_DIM * Y_DIM / 4);
    f32_to_bf16<<<dim3(512), blk, 0, stream>>>(dWhh0, dWhh0b, G_DIM * H_DIM / 4);
    f32_to_bf16<<<dim3(512), blk, 0, stream>>>(dWih1, dWih1b, G_DIM * H_DIM / 4);
    f32_to_bf16<<<dim3(512), blk, 0, stream>>>(dWhh1, dWhh1b, G_DIM * H_DIM / 4);
    f32_to_bf16<<<dim3(512), blk, 0, stream>>>(mapW, mapWb, Y_DIM * 2 * H_DIM / 4);

    init_kernel<<<dim3(BATCH * H_DIM / 256), blk, 0, stream>>>(
        h0f[0], h1f[0], h0b[0], h1b[0], loss_acc, ysum);
    ysum_kernel<<<dim3(2048), blk, 0, stream>>>(y, ysum, BATCH * T_OUT * Y_DIM);

    dim3 gCell(8, 16, 2);

    // -------- encoder: diagonal pipeline, launch k = layer0(k) || layer1(k-1) ----
    for (int k = 0; k <= T_IN; ++k) {
        CellArgs A = {}, B = {};
        A.active = (k < T_IN);
        if (A.active) {
            A.Af = emb; A.gat = x + k; A.gs = T_IN; A.lda = E_DIM; A.Kx = E_DIM;
            A.Wih = eWih0b; A.Whh = eWhh0b; A.bih = ebih0; A.bhh = ebhh0;
            A.hbf = h0b[k & 1]; A.hf = h0f[k & 1];
            A.houtf = h0f[(k + 1) & 1]; A.houtbf = h0b[(k + 1) & 1];
        }
        B.active = (k >= 1);
        if (B.active) {
            B.Ab = h0b[k & 1]; B.lda = H_DIM; B.Kx = H_DIM;
            B.Wih = eWih1b; B.Whh = eWhh1b; B.bih = ebih1; B.bhh = ebhh1;
            B.hbf = h1b[(k - 1) & 1]; B.hf = h1f[(k - 1) & 1];
            B.houtf = h1f[k & 1]; B.houtbf = h1b[k & 1];
            B.copy = enc_bf + (size_t)(k - 1) * BATCH * H_DIM;
        }
        cell_kernel<<<gCell, blk, 0, stream>>>(A, B);
    }

    // -------- decoder GRU chain (teacher-forced): same pipeline ----
    for (int k = 0; k <= T_OUT; ++k) {
        CellArgs A = {}, B = {};
        A.active = (k < T_OUT);
        if (A.active) {
            A.Af = (k == 0) ? nullptr : (y + (size_t)(k - 1) * Y_DIM);
            A.lda = T_OUT * Y_DIM; A.Kx = Y_DIM;
            A.Wih = dWih0b; A.Whh = dWhh0b; A.bih = dbih0; A.bhh = dbhh0;
            A.hbf = h0b[k & 1]; A.hf = h0f[k & 1];
            A.houtf = h0f[(k + 1) & 1]; A.houtbf = h0b[(k + 1) & 1];
        }
        B.active = (k >= 1);
        if (B.active) {
            B.Ab = h0b[k & 1]; B.lda = H_DIM; B.Kx = H_DIM;
            B.Wih = dWih1b; B.Whh = dWhh1b; B.bih = dbih1; B.bhh = dbhh1;
            B.hbf = h1b[(k - 1) & 1]; B.hf = h1f[(k - 1) & 1];
            B.houtf = h1f[k & 1]; B.houtbf = h1b[k & 1];
            B.copy = h2all + (size_t)(k - 1) * BATCH * H_DIM;
        }
        cell_kernel<<<gCell, blk, 0, stream>>>(A, B);
    }

    // -------- batched attention + map + loss over all 32 decoder steps ----
    score_gemm<<<dim3(4, 256), blk, 0, stream>>>(h2all, enc_bf, S);
    softmax_all<<<dim3(8192), blk, 0, stream>>>(S);
    attn_apply_all<<<dim3(4, 256), blk, 0, stream>>>(enc_bf, S, attn_bf);
    map_gemm<<<dim3(128, 16), blk, 0, stream>>>(attn_bf, h2all, mapWb, mapb, logits);
    loss_all<<<dim3(8192), blk, 0, stream>>>(logits, y, loss_acc);

    final_kernel<<<dim3(1), dim3(64), 0, stream>>>(loss_acc, ysum, out);
}